// Round 10
// baseline (375.705 us; speedup 1.0000x reference)
//
#include <hip/hip_runtime.h>
#include <cstdint>
#include <cstddef>

#define IN_CH 128
#define HID_CH 128
#define OUT_CH 64

typedef unsigned int uint32;
typedef unsigned char uchar;
typedef short bf16x8 __attribute__((ext_vector_type(8)));
typedef float f32x4 __attribute__((ext_vector_type(4)));
typedef float f32x2 __attribute__((ext_vector_type(2)));

// float -> bf16 round-to-nearest-even
static __device__ __forceinline__ unsigned short f2bf(float f) {
    uint32 u = __float_as_uint(f);
    u += 0x7fffu + ((u >> 16) & 1u);
    return (unsigned short)(u >> 16);
}

// async global->LDS, 16B per lane, register-free (compiler cannot serialize).
// Global source address is PER-LANE; LDS dest is wave-uniform base + lane*16.
typedef const __attribute__((address_space(1))) char gch;
typedef __attribute__((address_space(3))) char lch;
static __device__ __forceinline__ void gload16(const void* g, void* l) {
    __builtin_amdgcn_global_load_lds((gch*)g, (lch*)l, 16, 0, 0);
}

// ---------------- CSR build: 3-pass global-atomic (no pairBuf) ----------------
// k1 deg_wtrans : atomicAdd(&deg[dst],1) grid-stride (L2 atomics) + W transpose
// k2 scan_local : 256-node LDS scan of deg -> rowloc (bucket-local excl), bsum
// k3 bscan2     : 1-block scan of 391 bucket sums -> bbase
// k4 scatter    : csr[bbase[d>>8] + atomicAdd(&rowloc[d],1)] = src
// After k4: rowloc[v] = local_excl + deg[v]; consumers use
//   base(v) = bbase[v>>8] + rowloc[v] - deg[v].  dinv = rsqrtf(deg+2) computed
// in-register everywhere (dinv array deleted).

__global__ __launch_bounds__(256) void deg_wtrans(
    const int* __restrict__ dst, int* __restrict__ deg, int E, int gD,
    const float* __restrict__ W1, const float* __restrict__ W2,
    unsigned short* __restrict__ W1t, unsigned short* __restrict__ W2t) {
    if (blockIdx.x >= (uint32)gD) {
        int t = (blockIdx.x - gD) * 256 + threadIdx.x;
        if (t < 128 * 128) {
            int nc = t >> 7, k = t & 127;
            W1t[t] = f2bf(W1[k * 128 + nc]);
        }
        int u = t - 128 * 128;
        if (u >= 0 && u < 64 * 128) {
            int nc = u >> 7, k = u & 127;
            W2t[u] = f2bf(W2[k * 64 + nc]);
        }
        return;
    }
    int i0 = blockIdx.x * 256 + threadIdx.x;
    int stride = gD * 256;
    for (int i = i0; i < E; i += stride)
        atomicAdd(&deg[dst[i]], 1);
}

__global__ __launch_bounds__(256) void scan_local(
    const int* __restrict__ deg, int* __restrict__ rowloc,
    int* __restrict__ bsum, int N) {
    __shared__ int s[256];
    int b = blockIdx.x, t = threadIdx.x;
    int node = (b << 8) + t;
    int v = (node < N) ? deg[node] : 0;
    s[t] = v;
    __syncthreads();
    for (int o = 1; o < 256; o <<= 1) {
        int a = (t >= o) ? s[t - o] : 0;
        __syncthreads();
        s[t] += a;
        __syncthreads();
    }
    if (node < N) rowloc[node] = s[t] - v;
    if (t == 255) bsum[b] = s[t];
}

__global__ void bscan2(const int* __restrict__ bsum, int* __restrict__ bbase, int NB) {
    __shared__ int s[512];
    int t = threadIdx.x;
    int v = (t < NB) ? bsum[t] : 0;
    s[t] = v;
    __syncthreads();
    for (int o = 1; o < 512; o <<= 1) {
        int a = (t >= o) ? s[t - o] : 0;
        __syncthreads();
        s[t] += a;
        __syncthreads();
    }
    if (t < NB) bbase[t] = s[t] - v;
}

__global__ __launch_bounds__(256) void scatter(
    const int* __restrict__ src, const int* __restrict__ dst,
    const int* __restrict__ bbase, int* __restrict__ rowloc,
    int* __restrict__ csr, int E, int NB) {
    __shared__ int bb[512];
    int t = threadIdx.x;
    for (int b = t; b < NB; b += 256) bb[b] = bbase[b];
    __syncthreads();
    int i0 = blockIdx.x * 256 + t;
    int stride = gridDim.x * 256;
    for (int i = i0; i < E; i += stride) {
        int s = src[i], d = dst[i];
        int q = bb[d >> 8] + atomicAdd(&rowloc[d], 1);
        csr[q] = s;
    }
}

// ---------------- MFMA GEMM1: H1[n,128] = fp8(dinv[n] * (x[n,128] @ W1)) ----------
// m97-style staging (global_load_lds width=16, register-free) + OPERAND-SWAPPED
// MFMA: acc[nt][p] holds 4 CONSECUTIVE channels of ONE node -> dword fp8 stores.

__global__ __launch_bounds__(256) void gemm1_mfma(
    const float* __restrict__ A, const unsigned short* __restrict__ Wt,
    const int* __restrict__ degp, uchar* __restrict__ C, int n, int nTiles) {
    constexpr int NT = 8;                          // 128 out channels / 16
    __shared__ unsigned short Ws[128 * 136];       // padded W (34.8K)
    __shared__ char As[64 * 512];                  // 64-row fp32 tile (32K)

    const int t = threadIdx.x;

    // stage W once (padded pitch kills ds_read bank conflicts)
    for (int i = t; i < 128 * 16; i += 256) {
        int rr = i >> 4, sq = i & 15;
        *(uint4*)&Ws[rr * 136 + sq * 8] = *(const uint4*)(Wt + rr * 128 + sq * 8);
    }

    const int w = t >> 6, l = t & 63;
    const int q = l >> 4, r16 = l & 15;
    const int rw = w * 16 + r16;                   // this lane's node row in tile

    for (int tile = blockIdx.x; tile < nTiles; tile += gridDim.x) {
        const int row0 = tile * 64;

        // ---- stage A tile: linear LDS dest, per-lane clamped global source ----
#pragma unroll
        for (int rnd = 0; rnd < 8; rnd++) {
            int p = rnd * 4096 + t * 16;           // byte position in tile
            int row = row0 + (p >> 9);
            int col = p & 511;
            gload16((const char*)A + (size_t)min(row, n - 1) * 512 + col, As + p);
        }
        __syncthreads();   // drains vmcnt -> tile resident (and W on first iter)

        f32x4 acc[NT];
#pragma unroll
        for (int i = 0; i < NT; i++) acc[i] = (f32x4){0.f, 0.f, 0.f, 0.f};

#pragma unroll
        for (int s = 0; s < 4; s++) {
            const int k0 = s * 32 + q * 8;         // element k-offset
            // x-fragment (B operand: lane&15 -> node col)
            const float* Arow = (const float*)(As + rw * 512);
            float4 v0 = *(const float4*)(Arow + k0);
            float4 v1 = *(const float4*)(Arow + k0 + 4);
            bf16x8 xf;
            xf[0] = (short)f2bf(v0.x); xf[1] = (short)f2bf(v0.y);
            xf[2] = (short)f2bf(v0.z); xf[3] = (short)f2bf(v0.w);
            xf[4] = (short)f2bf(v1.x); xf[5] = (short)f2bf(v1.y);
            xf[6] = (short)f2bf(v1.z); xf[7] = (short)f2bf(v1.w);
#pragma unroll
            for (int nt = 0; nt < NT; nt++) {
                // W-fragment (A operand: lane&15 -> channel row)
                bf16x8 wf = *(const bf16x8*)&Ws[(nt * 16 + r16) * 136 + k0];
                acc[nt] = __builtin_amdgcn_mfma_f32_16x16x32_bf16(wf, xf, acc[nt], 0, 0, 0);
            }
        }

        // ---- epilogue: acc[nt][p] = channel (nt*16 + q*4 + p) of node rw ----
        const int node = row0 + rw;
        const bool nv = node < n;
        const int dgv = degp[min(node, n - 1)];
        const float dv = rsqrtf((float)(dgv + 2));
        uchar* Crow = C + (size_t)node * 128;
#pragma unroll
        for (int nt = 0; nt < NT; nt++) {
            int pk = 0;
            pk = __builtin_amdgcn_cvt_pk_fp8_f32(acc[nt][0] * dv, acc[nt][1] * dv, pk, false);
            pk = __builtin_amdgcn_cvt_pk_fp8_f32(acc[nt][2] * dv, acc[nt][3] * dv, pk, true);
            if (nv) *(uint32*)(Crow + nt * 16 + q * 4) = (uint32)pk;
        }
        __syncthreads();   // protect As from next tile's staging
    }
}

// ---------------- Fused agg1 + gemm2: pipelined LDS-staged gather ---------------
// Per 16-edge batch: issue 8x global_load_lds (8 KB, zero VGPR), then issue the
// NEXT batch's csr index load, then SPLIT-DRAIN: vmcnt(4) -> consume edges 0..7
// while edges 8..15 are still in flight; vmcnt(0) -> consume the rest.

__global__ __launch_bounds__(256) void agg1_fused(
    const uchar* __restrict__ H, const int* __restrict__ csr,
    const int* __restrict__ rowloc, const int* __restrict__ bbase,
    const int* __restrict__ deg, const float* __restrict__ bias,
    const unsigned short* __restrict__ W2t, uchar* __restrict__ H2, int n) {
    __shared__ char stage[4][8192];                // per-wave gather slices
    __shared__ unsigned short tile[16 * 136];      // 16 nodes x 128ch bf16, padded
    int t = threadIdx.x;
    int slot = t >> 4;                              // node slot in block (0..15)
    int v = blockIdx.x * 16 + slot;
    int hl = t & 15;
    int gsel = t & 48;
    int w = t >> 6;                                 // wave id
    int gg = (t >> 4) & 3;                          // group within wave
    bool valid = v < n;
    int vc = valid ? v : 0;
    int cnt = valid ? deg[vc] : 0;
    int base = bbase[vc >> 8] + rowloc[vc] - cnt;   // rowloc is post-scatter end

    f32x2 A0 = (f32x2){0.f, 0.f}, A1 = A0, A2 = A0, A3 = A0;
    f32x2 B0 = A0, B1 = A0, B2 = A0, B3 = A0;

#define ACC128(h, s0, s1, s2, s3)                                   \
    {                                                               \
        s0 += __builtin_amdgcn_cvt_pk_f32_fp8((h).x, false);        \
        s1 += __builtin_amdgcn_cvt_pk_f32_fp8((h).x, true);         \
        s2 += __builtin_amdgcn_cvt_pk_f32_fp8((h).y, false);        \
        s3 += __builtin_amdgcn_cvt_pk_f32_fp8((h).y, true);         \
    }

    char* sl = stage[w];
    const char* rg = sl + gg * 256 + hl * 8;       // consume base for this lane

    int ul = 0;
    if (hl < min(16, cnt)) ul = csr[base + hl];    // batch 0 indices

    for (int j0 = 0; j0 < cnt; j0 += 16) {
        int nj = min(16, cnt - j0);
        // ---- issue: 8x global_load_lds (8 KB in flight, no VGPR held) ----
#pragma unroll
        for (int i = 0; i < 8; i++) {
            int j = i * 2 + (hl >> 3);
            int u = __shfl(ul, j | gsel);
            gload16(H + (((uint32)u << 7) + ((uint32)(hl & 7) << 4)),
                    sl + i * 1024);
        }
        // ---- prefetch next batch's csr indices (drains under consume) ----
        int ul2 = 0;
        int j0n = j0 + 16;
        if (j0n < cnt && hl < min(16, cnt - j0n)) ul2 = csr[base + j0n + hl];
        // ---- split-drain consume ----
        asm volatile("s_waitcnt vmcnt(4)" ::: "memory");
        __builtin_amdgcn_sched_barrier(0);
#pragma unroll
        for (int j = 0; j < 8; j++) {
            if (j < nj) {
                uint2 h = *(const uint2*)(rg + (j >> 1) * 1024 + (j & 1) * 128);
                if (j & 1) { ACC128(h, B0, B1, B2, B3); }
                else       { ACC128(h, A0, A1, A2, A3); }
            }
        }
        asm volatile("s_waitcnt vmcnt(0)" ::: "memory");
        __builtin_amdgcn_sched_barrier(0);
#pragma unroll
        for (int j = 8; j < 16; j++) {
            if (j < nj) {
                uint2 h = *(const uint2*)(rg + (j >> 1) * 1024 + (j & 1) * 128);
                if (j & 1) { ACC128(h, B0, B1, B2, B3); }
                else       { ACC128(h, A0, A1, A2, A3); }
            }
        }
        ul = ul2;
    }
#undef ACC128

    // ---- finish hidden: self-loop + bias + ReLU, pack bf16 ----
    const uint32 co = (uint32)(hl * 8);
    uint4 pk = make_uint4(0, 0, 0, 0);
    if (valid) {
        float dv = rsqrtf((float)(cnt + 2));
        uint2 hv = *(const uint2*)(H + (((uint32)vc << 7) + co));
        f32x2 s0 = __builtin_amdgcn_cvt_pk_f32_fp8(hv.x, false);
        f32x2 s1 = __builtin_amdgcn_cvt_pk_f32_fp8(hv.x, true);
        f32x2 s2 = __builtin_amdgcn_cvt_pk_f32_fp8(hv.y, false);
        f32x2 s3 = __builtin_amdgcn_cvt_pk_f32_fp8(hv.y, true);
        const f32x2* bp = (const f32x2*)(bias + hl * 8);
        f32x2 e0 = dv * ((A0 + B0) + 2.f * s0) + bp[0];
        f32x2 e1 = dv * ((A1 + B1) + 2.f * s1) + bp[1];
        f32x2 e2 = dv * ((A2 + B2) + 2.f * s2) + bp[2];
        f32x2 e3 = dv * ((A3 + B3) + 2.f * s3) + bp[3];
        float o0 = fmaxf(e0[0], 0.f), o1 = fmaxf(e0[1], 0.f);
        float o2 = fmaxf(e1[0], 0.f), o3 = fmaxf(e1[1], 0.f);
        float o4 = fmaxf(e2[0], 0.f), o5 = fmaxf(e2[1], 0.f);
        float o6 = fmaxf(e3[0], 0.f), o7 = fmaxf(e3[1], 0.f);
        pk.x = (uint32)f2bf(o0) | ((uint32)f2bf(o1) << 16);
        pk.y = (uint32)f2bf(o2) | ((uint32)f2bf(o3) << 16);
        pk.z = (uint32)f2bf(o4) | ((uint32)f2bf(o5) << 16);
        pk.w = (uint32)f2bf(o6) | ((uint32)f2bf(o7) << 16);
    }
    *(uint4*)&tile[slot * 136 + hl * 8] = pk;
    __syncthreads();

    // ---- gemm2 tail: wave w -> channels w*16..+15 for all 16 nodes ----
    const int l = t & 63;
    const int q = l >> 4, r16 = l & 15;
    f32x4 acc2 = (f32x4){0.f, 0.f, 0.f, 0.f};
#pragma unroll
    for (int s = 0; s < 4; s++) {
        const int k0 = s * 32 + q * 8;
        bf16x8 hf = *(const bf16x8*)&tile[r16 * 136 + k0];                 // node r16
        bf16x8 wf = *(const bf16x8*)(W2t + (size_t)(w * 16 + r16) * 128 + k0); // channel
        acc2 = __builtin_amdgcn_mfma_f32_16x16x32_bf16(wf, hf, acc2, 0, 0, 0);
    }
    const int node = blockIdx.x * 16 + r16;
    if (node < n) {
        const float dv2 = rsqrtf((float)(deg[node] + 2));
        int pk2 = 0;
        pk2 = __builtin_amdgcn_cvt_pk_fp8_f32(acc2[0] * dv2, acc2[1] * dv2, pk2, false);
        pk2 = __builtin_amdgcn_cvt_pk_fp8_f32(acc2[2] * dv2, acc2[3] * dv2, pk2, true);
        *(uint32*)(H2 + (size_t)node * 64 + w * 16 + q * 4) = (uint32)pk2;
    }
}

// agg2: 64 ch; same pipelined LDS-staged gather (4 gloads/batch + csr prefetch,
// vmcnt(2)/vmcnt(0) split). log_softmax within group of 16.
__global__ __launch_bounds__(256) void agg_lsm_64(
    const uchar* __restrict__ H, const int* __restrict__ csr,
    const int* __restrict__ rowloc, const int* __restrict__ bbase,
    const int* __restrict__ deg, const float* __restrict__ bias,
    float* __restrict__ out, int n) {
    __shared__ char stage[4][4096];
    int t = threadIdx.x;
    int v = blockIdx.x * 16 + (t >> 4);
    int hl = t & 15;
    int gsel = t & 48;
    int w = t >> 6;
    int gg = (t >> 4) & 3;
    bool valid = v < n;
    int vc = valid ? v : 0;
    int cnt = valid ? deg[vc] : 0;
    int base = bbase[vc >> 8] + rowloc[vc] - cnt;
    const uint32 co = (uint32)(hl * 4);

    f32x2 A0 = (f32x2){0.f, 0.f}, A1 = A0, B0 = A0, B1 = A0;

#define ACC64(h, s0, s1)                                            \
    {                                                               \
        s0 += __builtin_amdgcn_cvt_pk_f32_fp8((h), false);          \
        s1 += __builtin_amdgcn_cvt_pk_f32_fp8((h), true);           \
    }

    char* sl = stage[w];
    const char* rg = sl + gg * 256 + hl * 4;

    int ul = 0;
    if (hl < min(16, cnt)) ul = csr[base + hl];

    for (int j0 = 0; j0 < cnt; j0 += 16) {
        int nj = min(16, cnt - j0);
#pragma unroll
        for (int i = 0; i < 4; i++) {
            int j = i * 4 + (hl >> 2);
            int u = __shfl(ul, j | gsel);
            gload16(H + (((uint32)u << 6) + ((uint32)(hl & 3) << 4)),
                    sl + i * 1024);
        }
        int ul2 = 0;
        int j0n = j0 + 16;
        if (j0n < cnt && hl < min(16, cnt - j0n)) ul2 = csr[base + j0n + hl];
        asm volatile("s_waitcnt vmcnt(2)" ::: "memory");
        __builtin_amdgcn_sched_barrier(0);
#pragma unroll
        for (int j = 0; j < 8; j++) {
            if (j < nj) {
                uint32 h = *(const uint32*)(rg + (j >> 2) * 1024 + (j & 3) * 64);
                if (j & 1) { ACC64(h, B0, B1); }
                else       { ACC64(h, A0, A1); }
            }
        }
        asm volatile("s_waitcnt vmcnt(0)" ::: "memory");
        __builtin_amdgcn_sched_barrier(0);
#pragma unroll
        for (int j = 8; j < 16; j++) {
            if (j < nj) {
                uint32 h = *(const uint32*)(rg + (j >> 2) * 1024 + (j & 3) * 64);
                if (j & 1) { ACC64(h, B0, B1); }
                else       { ACC64(h, A0, A1); }
            }
        }
        ul = ul2;
    }
#undef ACC64

    float dv = rsqrtf((float)(cnt + 2));
    uint32 hv = *(const uint32*)(H + (((uint32)vc << 6) + co));
    f32x2 s0 = __builtin_amdgcn_cvt_pk_f32_fp8(hv, false);
    f32x2 s1 = __builtin_amdgcn_cvt_pk_f32_fp8(hv, true);
    const f32x2* bp = (const f32x2*)(bias + hl * 4);
    f32x2 w0 = dv * ((A0 + B0) + 2.f * s0) + bp[0];
    f32x2 w1 = dv * ((A1 + B1) + 2.f * s1) + bp[1];
    float v0 = w0[0], v1 = w0[1], v2 = w1[0], v3 = w1[1];
    // log_softmax across the 64 channels held by this 16-lane group
    float m = fmaxf(fmaxf(v0, v1), fmaxf(v2, v3));
    for (int o = 8; o > 0; o >>= 1) m = fmaxf(m, __shfl_xor(m, o));
    float e = (__expf(v0 - m) + __expf(v1 - m)) + (__expf(v2 - m) + __expf(v3 - m));
    for (int o = 8; o > 0; o >>= 1) e += __shfl_xor(e, o);
    float ls = m + __logf(e);
    if (valid)
        *(float4*)(out + (size_t)vc * 64 + hl * 4) =
            make_float4(v0 - ls, v1 - ls, v2 - ls, v3 - ls);
}

// ---------------- launch ----------------

extern "C" void kernel_launch(void* const* d_in, const int* in_sizes, int n_in,
                              void* d_out, int out_size, void* d_ws, size_t ws_size,
                              hipStream_t stream) {
    const float* x  = (const float*)d_in[0];
    const int*   ei = (const int*)d_in[1];
    const float* W1 = (const float*)d_in[2];
    const float* b1 = (const float*)d_in[3];
    const float* W2 = (const float*)d_in[4];
    const float* b2 = (const float*)d_in[5];
    float* out = (float*)d_out;

    const int N = in_sizes[0] / IN_CH;  // 100000
    const int E = in_sizes[1] / 2;      // 1600000
    const int* src = ei;
    const int* dst = ei + E;
    const int NB = (N + 255) >> 8;      // 391 buckets of 256 nodes

    char* w = (char*)d_ws;
    size_t off = 0;
    auto alloc = [&](size_t bytes) -> char* {
        char* p = w + off;
        off = (off + bytes + 255) & ~(size_t)255;
        return p;
    };
    int*   deg    = (int*)alloc((size_t)N * 4);
    int*   rowloc = (int*)alloc((size_t)N * 4);
    int*   bsum   = (int*)alloc(512 * 4);
    int*   bbase  = (int*)alloc(512 * 4);
    int*   csr    = (int*)alloc((size_t)E * 4);              // 6.4 MB
    unsigned short* W1t = (unsigned short*)alloc(128 * 128 * 2);
    unsigned short* W2t = (unsigned short*)alloc(64 * 128 * 2);
    uchar* H1  = (uchar*)alloc((size_t)N * HID_CH);          // fp8, 12.8 MB
    uchar* H2  = (uchar*)alloc((size_t)N * OUT_CH);          // fp8, 6.4 MB

    hipMemsetAsync(deg, 0, (size_t)N * 4, stream);

    const int gD = 1024;                // deg-count blocks (grid-stride)
    deg_wtrans<<<gD + 96, 256, 0, stream>>>(dst, deg, E, gD, W1, W2, W1t, W2t);
    scan_local<<<NB, 256, 0, stream>>>(deg, rowloc, bsum, N);
    bscan2<<<1, 512, 0, stream>>>(bsum, bbase, NB);
    scatter<<<1024, 256, 0, stream>>>(src, dst, bbase, rowloc, csr, E, NB);

    const int nTiles = (N + 63) / 64;   // 1563
    const int gG = min(nTiles, 512);    // persistent grid-stride blocks
    gemm1_mfma<<<gG, 256, 0, stream>>>(x, W1t, deg, H1, N, nTiles);
    agg1_fused<<<(N + 15) / 16, 256, 0, stream>>>(H1, csr, rowloc, bbase, deg, b1, W2t, H2, N);
    agg_lsm_64<<<(N + 15) / 16, 256, 0, stream>>>(H2, csr, rowloc, bbase, deg, b2, out, N);
}

// Round 11
// 220.762 us; speedup vs baseline: 1.7019x; 1.7019x over previous
//
#include <hip/hip_runtime.h>
#include <cstdint>
#include <cstddef>

#define IN_CH 128
#define HID_CH 128
#define OUT_CH 64
#define BSH 8        // nodes per bucket = 256
#define PB 2048      // edges per partition block (512 threads -> 4 passes)
#define CAP 6144     // bucket segment capacity (mean 4092, +32 sigma)

typedef unsigned int uint32;
typedef unsigned char uchar;
typedef short bf16x8 __attribute__((ext_vector_type(8)));
typedef float f32x4 __attribute__((ext_vector_type(4)));
typedef float f32x2 __attribute__((ext_vector_type(2)));

// float -> bf16 round-to-nearest-even
static __device__ __forceinline__ unsigned short f2bf(float f) {
    uint32 u = __float_as_uint(f);
    u += 0x7fffu + ((u >> 16) & 1u);
    return (unsigned short)(u >> 16);
}

// async global->LDS, 16B per lane, register-free (compiler cannot serialize).
// Global source address is PER-LANE; LDS dest is wave-uniform base + lane*16.
typedef const __attribute__((address_space(1))) char gch;
typedef __attribute__((address_space(3))) char lch;
static __device__ __forceinline__ void gload16(const void* g, void* l) {
    __builtin_amdgcn_global_load_lds((gch*)g, (lch*)l, 16, 0, 0);
}

// ---------------- CSR build: single-pass segmented buckets (512 threads) -------
// part1_wtrans: per-block LDS histogram -> one atomicAdd per touched bucket
// claims space in the bucket's FIXED segment (b*CAP) -> grouped scatter.
// LDS-buffered grouped writes avoid the R10 write-amplification failure
// (random 4B scatter = 106 MB WRITE_SIZE for a 6.4 MB array).

__global__ __launch_bounds__(512) void part1_wtrans(
    const int* __restrict__ src, const int* __restrict__ dst,
    int* __restrict__ bcur, int2* __restrict__ pairBuf, int E, int NB, int gP,
    const float* __restrict__ W1, const float* __restrict__ W2,
    unsigned short* __restrict__ W1t, unsigned short* __restrict__ W2t) {
    if (blockIdx.x >= (uint32)gP) {
        int t = (blockIdx.x - gP) * 512 + threadIdx.x;
        if (t < 128 * 128) {
            int nc = t >> 7, k = t & 127;
            W1t[t] = f2bf(W1[k * 128 + nc]);
        }
        int u = t - 128 * 128;
        if (u >= 0 && u < 64 * 128) {
            int nc = u >> 7, k = u & 127;
            W2t[u] = f2bf(W2[k * 64 + nc]);
        }
        return;
    }
    __shared__ int2 pairs[PB];          // 16 KB
    __shared__ int hist[512];
    __shared__ int base[512];
    int t = threadIdx.x;
    int e0 = blockIdx.x * PB;
    int cnt = min(PB, E - e0);
    for (int b = t; b < NB; b += 512) hist[b] = 0;
    __syncthreads();
    for (int i = t; i < cnt; i += 512) {
        int s = src[e0 + i], d = dst[e0 + i];
        pairs[i] = make_int2(s, d);
        atomicAdd(&hist[d >> BSH], 1);
    }
    __syncthreads();
    for (int b = t; b < NB; b += 512) {
        int h = hist[b];
        int gb = (h > 0) ? atomicAdd(&bcur[b], h) : 0;
        base[b] = b * CAP + gb;
        hist[b] = 0;
    }
    __syncthreads();
    for (int i = t; i < cnt; i += 512) {
        int2 p = pairs[i];
        int b = p.y >> BSH;
        int q = base[b] + atomicAdd(&hist[b], 1);
        pairBuf[q] = p;
    }
}

__global__ __launch_bounds__(512) void bucket_build(
    const int2* __restrict__ pairBuf, const int* __restrict__ bcur,
    int* __restrict__ rowptr, int* __restrict__ deg, float* __restrict__ dinv,
    int* __restrict__ csr, int N) {
    __shared__ int cnt[256];
    __shared__ int loc[256];
    int b = blockIdx.x, t = threadIdx.x;
    int start = b * CAP, end = start + bcur[b];
    if (t < 256) cnt[t] = 0;
    __syncthreads();
    for (int i = start + t; i < end; i += 512)
        atomicAdd(&cnt[pairBuf[i].y & 255], 1);
    __syncthreads();
    int v = 0;
    if (t < 256) { v = cnt[t]; loc[t] = v; }
    __syncthreads();
    for (int o = 1; o < 256; o <<= 1) {
        int add = (t < 256 && t >= o) ? loc[t - o] : 0;
        __syncthreads();
        if (t < 256) loc[t] += add;
        __syncthreads();
    }
    if (t < 256) {
        int excl = loc[t] - v;
        int node = (b << BSH) + t;
        if (node < N) {
            rowptr[node] = start + excl;
            deg[node] = v;
            dinv[node] = rsqrtf((float)(v + 2));   // +2 self-loops
        }
        cnt[t] = excl;                              // reuse as cursor
    }
    __syncthreads();
    for (int i = start + t; i < end; i += 512) {
        int2 p = pairBuf[i];
        int q = start + atomicAdd(&cnt[p.y & 255], 1);
        csr[q] = p.x;
    }
}

// ---------------- MFMA GEMM1: H1[n,128] = fp8(dinv[n] * (x[n,128] @ W1)) ----------
// m97-style staging (global_load_lds width=16, register-free) + OPERAND-SWAPPED
// MFMA: acc[nt][p] holds 4 CONSECUTIVE channels of ONE node -> dword fp8 stores.

__global__ __launch_bounds__(256) void gemm1_mfma(
    const float* __restrict__ A, const unsigned short* __restrict__ Wt,
    const float* __restrict__ dinv, uchar* __restrict__ C, int n, int nTiles) {
    constexpr int NT = 8;                          // 128 out channels / 16
    __shared__ unsigned short Ws[128 * 136];       // padded W (34.8K)
    __shared__ char As[64 * 512];                  // 64-row fp32 tile (32K)

    const int t = threadIdx.x;

    // stage W once (padded pitch kills ds_read bank conflicts)
    for (int i = t; i < 128 * 16; i += 256) {
        int rr = i >> 4, sq = i & 15;
        *(uint4*)&Ws[rr * 136 + sq * 8] = *(const uint4*)(Wt + rr * 128 + sq * 8);
    }

    const int w = t >> 6, l = t & 63;
    const int q = l >> 4, r16 = l & 15;
    const int rw = w * 16 + r16;                   // this lane's node row in tile

    for (int tile = blockIdx.x; tile < nTiles; tile += gridDim.x) {
        const int row0 = tile * 64;

        // ---- stage A tile: linear LDS dest, per-lane clamped global source ----
#pragma unroll
        for (int rnd = 0; rnd < 8; rnd++) {
            int p = rnd * 4096 + t * 16;           // byte position in tile
            int row = row0 + (p >> 9);
            int col = p & 511;
            gload16((const char*)A + (size_t)min(row, n - 1) * 512 + col, As + p);
        }
        __syncthreads();   // drains vmcnt -> tile resident (and W on first iter)

        f32x4 acc[NT];
#pragma unroll
        for (int i = 0; i < NT; i++) acc[i] = (f32x4){0.f, 0.f, 0.f, 0.f};

#pragma unroll
        for (int s = 0; s < 4; s++) {
            const int k0 = s * 32 + q * 8;         // element k-offset
            // x-fragment (B operand: lane&15 -> node col)
            const float* Arow = (const float*)(As + rw * 512);
            float4 v0 = *(const float4*)(Arow + k0);
            float4 v1 = *(const float4*)(Arow + k0 + 4);
            bf16x8 xf;
            xf[0] = (short)f2bf(v0.x); xf[1] = (short)f2bf(v0.y);
            xf[2] = (short)f2bf(v0.z); xf[3] = (short)f2bf(v0.w);
            xf[4] = (short)f2bf(v1.x); xf[5] = (short)f2bf(v1.y);
            xf[6] = (short)f2bf(v1.z); xf[7] = (short)f2bf(v1.w);
#pragma unroll
            for (int nt = 0; nt < NT; nt++) {
                // W-fragment (A operand: lane&15 -> channel row)
                bf16x8 wf = *(const bf16x8*)&Ws[(nt * 16 + r16) * 136 + k0];
                acc[nt] = __builtin_amdgcn_mfma_f32_16x16x32_bf16(wf, xf, acc[nt], 0, 0, 0);
            }
        }

        // ---- epilogue: acc[nt][p] = channel (nt*16 + q*4 + p) of node rw ----
        const int node = row0 + rw;
        const bool nv = node < n;
        const float dv = dinv[min(node, n - 1)];
        uchar* Crow = C + (size_t)node * 128;
#pragma unroll
        for (int nt = 0; nt < NT; nt++) {
            int pk = 0;
            pk = __builtin_amdgcn_cvt_pk_fp8_f32(acc[nt][0] * dv, acc[nt][1] * dv, pk, false);
            pk = __builtin_amdgcn_cvt_pk_fp8_f32(acc[nt][2] * dv, acc[nt][3] * dv, pk, true);
            if (nv) *(uint32*)(Crow + nt * 16 + q * 4) = (uint32)pk;
        }
        __syncthreads();   // protect As from next tile's staging
    }
}

// ---------------- Fused agg1 + gemm2: pipelined LDS-staged gather ---------------
// Per 16-edge batch: issue 8x global_load_lds (8 KB, zero VGPR), then issue the
// NEXT batch's csr index load, then SPLIT-DRAIN: vmcnt(4) -> consume edges 0..7
// while edges 8..15 are still in flight; vmcnt(0) -> consume the rest.

__global__ __launch_bounds__(256) void agg1_fused(
    const uchar* __restrict__ H, const int* __restrict__ csr,
    const int* __restrict__ rowptr, const int* __restrict__ deg,
    const float* __restrict__ dinv, const float* __restrict__ bias,
    const unsigned short* __restrict__ W2t, uchar* __restrict__ H2, int n) {
    __shared__ char stage[4][8192];                // per-wave gather slices
    __shared__ unsigned short tile[16 * 136];      // 16 nodes x 128ch bf16, padded
    int t = threadIdx.x;
    int slot = t >> 4;                              // node slot in block (0..15)
    int v = blockIdx.x * 16 + slot;
    int hl = t & 15;
    int gsel = t & 48;
    int w = t >> 6;                                 // wave id
    int gg = (t >> 4) & 3;                          // group within wave
    bool valid = v < n;
    int vc = valid ? v : 0;
    int base = rowptr[vc];
    int cnt = valid ? deg[vc] : 0;

    f32x2 A0 = (f32x2){0.f, 0.f}, A1 = A0, A2 = A0, A3 = A0;
    f32x2 B0 = A0, B1 = A0, B2 = A0, B3 = A0;

#define ACC128(h, s0, s1, s2, s3)                                   \
    {                                                               \
        s0 += __builtin_amdgcn_cvt_pk_f32_fp8((h).x, false);        \
        s1 += __builtin_amdgcn_cvt_pk_f32_fp8((h).x, true);         \
        s2 += __builtin_amdgcn_cvt_pk_f32_fp8((h).y, false);        \
        s3 += __builtin_amdgcn_cvt_pk_f32_fp8((h).y, true);         \
    }

    char* sl = stage[w];
    const char* rg = sl + gg * 256 + hl * 8;       // consume base for this lane

    int ul = 0;
    if (hl < min(16, cnt)) ul = csr[base + hl];    // batch 0 indices

    for (int j0 = 0; j0 < cnt; j0 += 16) {
        int nj = min(16, cnt - j0);
        // ---- issue: 8x global_load_lds (8 KB in flight, no VGPR held) ----
#pragma unroll
        for (int i = 0; i < 8; i++) {
            int j = i * 2 + (hl >> 3);
            int u = __shfl(ul, j | gsel);
            gload16(H + (((uint32)u << 7) + ((uint32)(hl & 7) << 4)),
                    sl + i * 1024);
        }
        // ---- prefetch next batch's csr indices (drains under consume) ----
        int ul2 = 0;
        int j0n = j0 + 16;
        if (j0n < cnt && hl < min(16, cnt - j0n)) ul2 = csr[base + j0n + hl];
        // ---- split-drain consume ----
        asm volatile("s_waitcnt vmcnt(4)" ::: "memory");
        __builtin_amdgcn_sched_barrier(0);
#pragma unroll
        for (int j = 0; j < 8; j++) {
            if (j < nj) {
                uint2 h = *(const uint2*)(rg + (j >> 1) * 1024 + (j & 1) * 128);
                if (j & 1) { ACC128(h, B0, B1, B2, B3); }
                else       { ACC128(h, A0, A1, A2, A3); }
            }
        }
        asm volatile("s_waitcnt vmcnt(0)" ::: "memory");
        __builtin_amdgcn_sched_barrier(0);
#pragma unroll
        for (int j = 8; j < 16; j++) {
            if (j < nj) {
                uint2 h = *(const uint2*)(rg + (j >> 1) * 1024 + (j & 1) * 128);
                if (j & 1) { ACC128(h, B0, B1, B2, B3); }
                else       { ACC128(h, A0, A1, A2, A3); }
            }
        }
        ul = ul2;
    }
#undef ACC128

    // ---- finish hidden: self-loop + bias + ReLU, pack bf16 ----
    const uint32 co = (uint32)(hl * 8);
    uint4 pk = make_uint4(0, 0, 0, 0);
    if (valid) {
        float dv = dinv[vc];
        uint2 hv = *(const uint2*)(H + (((uint32)vc << 7) + co));
        f32x2 s0 = __builtin_amdgcn_cvt_pk_f32_fp8(hv.x, false);
        f32x2 s1 = __builtin_amdgcn_cvt_pk_f32_fp8(hv.x, true);
        f32x2 s2 = __builtin_amdgcn_cvt_pk_f32_fp8(hv.y, false);
        f32x2 s3 = __builtin_amdgcn_cvt_pk_f32_fp8(hv.y, true);
        const f32x2* bp = (const f32x2*)(bias + hl * 8);
        f32x2 e0 = dv * ((A0 + B0) + 2.f * s0) + bp[0];
        f32x2 e1 = dv * ((A1 + B1) + 2.f * s1) + bp[1];
        f32x2 e2 = dv * ((A2 + B2) + 2.f * s2) + bp[2];
        f32x2 e3 = dv * ((A3 + B3) + 2.f * s3) + bp[3];
        float o0 = fmaxf(e0[0], 0.f), o1 = fmaxf(e0[1], 0.f);
        float o2 = fmaxf(e1[0], 0.f), o3 = fmaxf(e1[1], 0.f);
        float o4 = fmaxf(e2[0], 0.f), o5 = fmaxf(e2[1], 0.f);
        float o6 = fmaxf(e3[0], 0.f), o7 = fmaxf(e3[1], 0.f);
        pk.x = (uint32)f2bf(o0) | ((uint32)f2bf(o1) << 16);
        pk.y = (uint32)f2bf(o2) | ((uint32)f2bf(o3) << 16);
        pk.z = (uint32)f2bf(o4) | ((uint32)f2bf(o5) << 16);
        pk.w = (uint32)f2bf(o6) | ((uint32)f2bf(o7) << 16);
    }
    *(uint4*)&tile[slot * 136 + hl * 8] = pk;
    __syncthreads();

    // ---- gemm2 tail: wave w -> channels w*16..+15 for all 16 nodes ----
    const int l = t & 63;
    const int q = l >> 4, r16 = l & 15;
    f32x4 acc2 = (f32x4){0.f, 0.f, 0.f, 0.f};
#pragma unroll
    for (int s = 0; s < 4; s++) {
        const int k0 = s * 32 + q * 8;
        bf16x8 hf = *(const bf16x8*)&tile[r16 * 136 + k0];                 // node r16
        bf16x8 wf = *(const bf16x8*)(W2t + (size_t)(w * 16 + r16) * 128 + k0); // channel
        acc2 = __builtin_amdgcn_mfma_f32_16x16x32_bf16(wf, hf, acc2, 0, 0, 0);
    }
    const int node = blockIdx.x * 16 + r16;
    if (node < n) {
        const float dv2 = dinv[node];
        int pk2 = 0;
        pk2 = __builtin_amdgcn_cvt_pk_fp8_f32(acc2[0] * dv2, acc2[1] * dv2, pk2, false);
        pk2 = __builtin_amdgcn_cvt_pk_fp8_f32(acc2[2] * dv2, acc2[3] * dv2, pk2, true);
        *(uint32*)(H2 + (size_t)node * 64 + w * 16 + q * 4) = (uint32)pk2;
    }
}

// agg2: 64 ch; same pipelined LDS-staged gather (4 gloads/batch + csr prefetch,
// vmcnt(2)/vmcnt(0) split). log_softmax within group of 16.
__global__ __launch_bounds__(256) void agg_lsm_64(
    const uchar* __restrict__ H, const int* __restrict__ csr,
    const int* __restrict__ rowptr, const int* __restrict__ deg,
    const float* __restrict__ dinv, const float* __restrict__ bias,
    float* __restrict__ out, int n) {
    __shared__ char stage[4][4096];
    int t = threadIdx.x;
    int v = blockIdx.x * 16 + (t >> 4);
    int hl = t & 15;
    int gsel = t & 48;
    int w = t >> 6;
    int gg = (t >> 4) & 3;
    bool valid = v < n;
    int vc = valid ? v : 0;
    int base = rowptr[vc];
    int cnt = valid ? deg[vc] : 0;
    const uint32 co = (uint32)(hl * 4);

    f32x2 A0 = (f32x2){0.f, 0.f}, A1 = A0, B0 = A0, B1 = A0;

#define ACC64(h, s0, s1)                                            \
    {                                                               \
        s0 += __builtin_amdgcn_cvt_pk_f32_fp8((h), false);          \
        s1 += __builtin_amdgcn_cvt_pk_f32_fp8((h), true);           \
    }

    char* sl = stage[w];
    const char* rg = sl + gg * 256 + hl * 4;

    int ul = 0;
    if (hl < min(16, cnt)) ul = csr[base + hl];

    for (int j0 = 0; j0 < cnt; j0 += 16) {
        int nj = min(16, cnt - j0);
#pragma unroll
        for (int i = 0; i < 4; i++) {
            int j = i * 4 + (hl >> 2);
            int u = __shfl(ul, j | gsel);
            gload16(H + (((uint32)u << 6) + ((uint32)(hl & 3) << 4)),
                    sl + i * 1024);
        }
        int ul2 = 0;
        int j0n = j0 + 16;
        if (j0n < cnt && hl < min(16, cnt - j0n)) ul2 = csr[base + j0n + hl];
        asm volatile("s_waitcnt vmcnt(2)" ::: "memory");
        __builtin_amdgcn_sched_barrier(0);
#pragma unroll
        for (int j = 0; j < 8; j++) {
            if (j < nj) {
                uint32 h = *(const uint32*)(rg + (j >> 2) * 1024 + (j & 3) * 64);
                if (j & 1) { ACC64(h, B0, B1); }
                else       { ACC64(h, A0, A1); }
            }
        }
        asm volatile("s_waitcnt vmcnt(0)" ::: "memory");
        __builtin_amdgcn_sched_barrier(0);
#pragma unroll
        for (int j = 8; j < 16; j++) {
            if (j < nj) {
                uint32 h = *(const uint32*)(rg + (j >> 2) * 1024 + (j & 3) * 64);
                if (j & 1) { ACC64(h, B0, B1); }
                else       { ACC64(h, A0, A1); }
            }
        }
        ul = ul2;
    }
#undef ACC64

    float dv = dinv[vc];
    uint32 hv = *(const uint32*)(H + (((uint32)vc << 6) + co));
    f32x2 s0 = __builtin_amdgcn_cvt_pk_f32_fp8(hv, false);
    f32x2 s1 = __builtin_amdgcn_cvt_pk_f32_fp8(hv, true);
    const f32x2* bp = (const f32x2*)(bias + hl * 4);
    f32x2 w0 = dv * ((A0 + B0) + 2.f * s0) + bp[0];
    f32x2 w1 = dv * ((A1 + B1) + 2.f * s1) + bp[1];
    float v0 = w0[0], v1 = w0[1], v2 = w1[0], v3 = w1[1];
    // log_softmax across the 64 channels held by this 16-lane group
    float m = fmaxf(fmaxf(v0, v1), fmaxf(v2, v3));
    for (int o = 8; o > 0; o >>= 1) m = fmaxf(m, __shfl_xor(m, o));
    float e = (__expf(v0 - m) + __expf(v1 - m)) + (__expf(v2 - m) + __expf(v3 - m));
    for (int o = 8; o > 0; o >>= 1) e += __shfl_xor(e, o);
    float ls = m + __logf(e);
    if (valid)
        *(float4*)(out + (size_t)vc * 64 + hl * 4) =
            make_float4(v0 - ls, v1 - ls, v2 - ls, v3 - ls);
}

// ---------------- launch ----------------

extern "C" void kernel_launch(void* const* d_in, const int* in_sizes, int n_in,
                              void* d_out, int out_size, void* d_ws, size_t ws_size,
                              hipStream_t stream) {
    const float* x  = (const float*)d_in[0];
    const int*   ei = (const int*)d_in[1];
    const float* W1 = (const float*)d_in[2];
    const float* b1 = (const float*)d_in[3];
    const float* W2 = (const float*)d_in[4];
    const float* b2 = (const float*)d_in[5];
    float* out = (float*)d_out;

    const int N = in_sizes[0] / IN_CH;  // 100000
    const int E = in_sizes[1] / 2;      // 1600000
    const int* src = ei;
    const int* dst = ei + E;
    const int NB = (N + 255) >> BSH;    // 391 buckets

    char* w = (char*)d_ws;
    size_t off = 0;
    auto alloc = [&](size_t bytes) -> char* {
        char* p = w + off;
        off = (off + bytes + 255) & ~(size_t)255;
        return p;
    };
    int*   deg    = (int*)alloc((size_t)N * 4);
    int*   rowptr = (int*)alloc((size_t)N * 4);
    int*   bcur   = (int*)alloc(512 * 4);
    float* dinv   = (float*)alloc((size_t)N * 4 + 1024);  // +pad for vector tails
    int*   csr    = (int*)alloc((size_t)NB * CAP * 4);    // segmented, 9.6 MB
    unsigned short* W1t = (unsigned short*)alloc(128 * 128 * 2);
    unsigned short* W2t = (unsigned short*)alloc(64 * 128 * 2);
    uchar* H1  = (uchar*)alloc((size_t)N * HID_CH);          // fp8, 12.8 MB
    char*  scratch = alloc((size_t)NB * CAP * 8);            // pairBuf then H2 (19.2 MB)
    uchar* H2  = (uchar*)scratch;        // fp8, 6.4 MB (pairBuf dead after bucket_build)
    int2*  pairBuf = (int2*)scratch;

    hipMemsetAsync(bcur, 0, 512 * 4, stream);

    int gP = (E + PB - 1) / PB;         // 782 partition blocks (512 threads each)
    int gW = (128 * 128 + 64 * 128 + 511) / 512;  // 48 W-transpose tail blocks

    part1_wtrans<<<gP + gW, 512, 0, stream>>>(src, dst, bcur, pairBuf, E, NB, gP,
                                              W1, W2, W1t, W2t);
    bucket_build<<<NB, 512, 0, stream>>>(pairBuf, bcur, rowptr, deg, dinv, csr, N);

    const int nTiles = (N + 63) / 64;   // 1563
    const int gG = min(nTiles, 512);    // persistent grid-stride blocks
    gemm1_mfma<<<gG, 256, 0, stream>>>(x, W1t, dinv, H1, N, nTiles);
    agg1_fused<<<(N + 15) / 16, 256, 0, stream>>>(H1, csr, rowptr, deg, dinv, b1, W2t, H2, N);
    agg_lsm_64<<<(N + 15) / 16, 256, 0, stream>>>(H2, csr, rowptr, deg, dinv, b2, out, N);
}

// Round 12
// 216.230 us; speedup vs baseline: 1.7375x; 1.0210x over previous
//
#include <hip/hip_runtime.h>
#include <cstdint>
#include <cstddef>

#define IN_CH 128
#define HID_CH 128
#define OUT_CH 64
#define BSH 8        // nodes per bucket = 256
#define PB 4096      // edges per partition block
#define CAP 6144     // bucket segment capacity (mean 4092, +32 sigma)

typedef unsigned int uint32;
typedef unsigned char uchar;
typedef short bf16x8 __attribute__((ext_vector_type(8)));
typedef float f32x4 __attribute__((ext_vector_type(4)));
typedef float f32x2 __attribute__((ext_vector_type(2)));

// float -> bf16 round-to-nearest-even
static __device__ __forceinline__ unsigned short f2bf(float f) {
    uint32 u = __float_as_uint(f);
    u += 0x7fffu + ((u >> 16) & 1u);
    return (unsigned short)(u >> 16);
}

// async global->LDS, 16B per lane, register-free (compiler cannot serialize).
// Global source address is PER-LANE; LDS dest is wave-uniform base + lane*16.
typedef const __attribute__((address_space(1))) char gch;
typedef __attribute__((address_space(3))) char lch;
static __device__ __forceinline__ void gload16(const void* g, void* l) {
    __builtin_amdgcn_global_load_lds((gch*)g, (lch*)l, 16, 0, 0);
}

// ---------------- CSR build: single-pass segmented buckets (R9 structure) -------
// part1_wtrans: per-block LDS histogram -> one atomicAdd per touched bucket
// claims space in the bucket's FIXED segment (b*CAP) -> grouped scatter.
// LDS-buffered grouped writes avoid the R10 write-amplification failure.

__global__ __launch_bounds__(256) void part1_wtrans(
    const int* __restrict__ src, const int* __restrict__ dst,
    int* __restrict__ bcur, int2* __restrict__ pairBuf, int E, int NB, int gP,
    const float* __restrict__ W1, const float* __restrict__ W2,
    unsigned short* __restrict__ W1t, unsigned short* __restrict__ W2t) {
    if (blockIdx.x >= (uint32)gP) {
        int t = (blockIdx.x - gP) * 256 + threadIdx.x;
        if (t < 128 * 128) {
            int nc = t >> 7, k = t & 127;
            W1t[t] = f2bf(W1[k * 128 + nc]);
        }
        int u = t - 128 * 128;
        if (u >= 0 && u < 64 * 128) {
            int nc = u >> 7, k = u & 127;
            W2t[u] = f2bf(W2[k * 64 + nc]);
        }
        return;
    }
    __shared__ int2 pairs[PB];          // 32 KB
    __shared__ int hist[512];
    __shared__ int base[512];
    int t = threadIdx.x;
    int e0 = blockIdx.x * PB;
    int cnt = min(PB, E - e0);
    for (int b = t; b < NB; b += 256) hist[b] = 0;
    __syncthreads();
    for (int i = t; i < cnt; i += 256) {
        int s = src[e0 + i], d = dst[e0 + i];
        pairs[i] = make_int2(s, d);
        atomicAdd(&hist[d >> BSH], 1);
    }
    __syncthreads();
    for (int b = t; b < NB; b += 256) {
        int h = hist[b];
        int gb = (h > 0) ? atomicAdd(&bcur[b], h) : 0;
        base[b] = b * CAP + gb;
        hist[b] = 0;
    }
    __syncthreads();
    for (int i = t; i < cnt; i += 256) {
        int2 p = pairs[i];
        int b = p.y >> BSH;
        int q = base[b] + atomicAdd(&hist[b], 1);
        pairBuf[q] = p;
    }
}

__global__ __launch_bounds__(256) void bucket_build(
    const int2* __restrict__ pairBuf, const int* __restrict__ bcur,
    int* __restrict__ rowptr, int* __restrict__ deg, float* __restrict__ dinv,
    int* __restrict__ csr, int N) {
    __shared__ int cnt[256];
    __shared__ int loc[256];
    int b = blockIdx.x, t = threadIdx.x;
    int start = b * CAP, end = start + bcur[b];
    cnt[t] = 0;
    __syncthreads();
    for (int i = start + t; i < end; i += 256)
        atomicAdd(&cnt[pairBuf[i].y & 255], 1);
    __syncthreads();
    int v = cnt[t];
    loc[t] = v;
    __syncthreads();
    for (int o = 1; o < 256; o <<= 1) {
        int add = (t >= o) ? loc[t - o] : 0;
        __syncthreads();
        loc[t] += add;
        __syncthreads();
    }
    int excl = loc[t] - v;
    int node = (b << BSH) + t;
    if (node < N) {
        rowptr[node] = start + excl;
        deg[node] = v;
        dinv[node] = rsqrtf((float)(v + 2));   // +2 self-loops
    }
    __syncthreads();
    cnt[t] = excl;                              // reuse as cursor
    __syncthreads();
    for (int i = start + t; i < end; i += 256) {
        int2 p = pairBuf[i];
        int q = start + atomicAdd(&cnt[p.y & 255], 1);
        csr[q] = p.x;
    }
}

// ---------------- MFMA GEMM1: H1[n,128] = fp8(dinv[n] * (x[n,128] @ W1)) ----------
// BARRIER-FREE wave-autonomous staging: each wave only consumes its OWN 16 rows
// (operand-swapped layout), so it stages them into a wave-PRIVATE LDS slice via
// 9x global_load_lds and waits with a wave-local vmcnt(0) -- no __syncthreads in
// the loop, waves drift independently across grid-strided tiles. Row pitch 528B
// (132 dwords == 4 mod 32) makes the 16-row fragment ds_reads a uniform 8-quad
// pattern (2 lanes/bank = free) vs the old 512B pitch's 4-quad 16-way pile-up.
// Pad columns are sourced with wrapped addresses (LDS dest must stay linear).

__global__ __launch_bounds__(256) void gemm1_mfma(
    const float* __restrict__ A, const unsigned short* __restrict__ Wt,
    const float* __restrict__ dinv, uchar* __restrict__ C, int n, int nTiles) {
    constexpr int NT = 8;                          // 128 out channels / 16
    constexpr int RP = 528;                        // padded row pitch bytes
    __shared__ unsigned short Ws[128 * 136];       // padded W (34.8K)
    __shared__ char As[4 * 9216];                  // 4 wave-private slices (36K)

    const int t = threadIdx.x;

    // stage W once (padded pitch: conflict-free b128 reads)
    for (int i = t; i < 128 * 16; i += 256) {
        int rr = i >> 4, sq = i & 15;
        *(uint4*)&Ws[rr * 136 + sq * 8] = *(const uint4*)(Wt + rr * 128 + sq * 8);
    }
    __syncthreads();                               // the ONLY barrier

    const int w = t >> 6, l = t & 63;
    const int q = l >> 4, r16 = l & 15;
    char* slice = As + w * 9216;
    const char* myrow = slice + r16 * RP;

    for (int tile = blockIdx.x; tile < nTiles; tile += gridDim.x) {
        const int row0 = tile * 64 + w * 16;       // this wave's first node

        // ---- stage this wave's 16 rows (padded pitch via clamped source) ----
#pragma unroll
        for (int rnd = 0; rnd < 9; rnd++) {
            int p = rnd * 1024 + l * 16;           // byte position in slice
            int row = p / RP;                      // magic-div (const)
            int col = (p - row * RP) & 511;        // pad cols wrap (never read)
            int rg = min(row0 + min(row, 15), n - 1);
            gload16((const char*)A + (size_t)rg * 512 + col, slice + p);
        }
        asm volatile("s_waitcnt vmcnt(0)" ::: "memory");
        __builtin_amdgcn_sched_barrier(0);

        f32x4 acc[NT];
#pragma unroll
        for (int i = 0; i < NT; i++) acc[i] = (f32x4){0.f, 0.f, 0.f, 0.f};

#pragma unroll
        for (int s = 0; s < 4; s++) {
            const int k0 = s * 32 + q * 8;         // element k-offset
            float4 v0 = *(const float4*)(myrow + k0 * 4);
            float4 v1 = *(const float4*)(myrow + k0 * 4 + 16);
            bf16x8 xf;
            xf[0] = (short)f2bf(v0.x); xf[1] = (short)f2bf(v0.y);
            xf[2] = (short)f2bf(v0.z); xf[3] = (short)f2bf(v0.w);
            xf[4] = (short)f2bf(v1.x); xf[5] = (short)f2bf(v1.y);
            xf[6] = (short)f2bf(v1.z); xf[7] = (short)f2bf(v1.w);
#pragma unroll
            for (int nt = 0; nt < NT; nt++) {
                bf16x8 wf = *(const bf16x8*)&Ws[(nt * 16 + r16) * 136 + k0];
                acc[nt] = __builtin_amdgcn_mfma_f32_16x16x32_bf16(wf, xf, acc[nt], 0, 0, 0);
            }
        }

        // ---- epilogue: acc[nt][p] = channel (nt*16 + q*4 + p) of node ----
        const int node = row0 + r16;
        const bool nv = node < n;
        const float dv = dinv[min(node, n - 1)];
        uchar* Crow = C + (size_t)node * 128;
#pragma unroll
        for (int nt = 0; nt < NT; nt++) {
            int pk = 0;
            pk = __builtin_amdgcn_cvt_pk_fp8_f32(acc[nt][0] * dv, acc[nt][1] * dv, pk, false);
            pk = __builtin_amdgcn_cvt_pk_fp8_f32(acc[nt][2] * dv, acc[nt][3] * dv, pk, true);
            if (nv) *(uint32*)(Crow + nt * 16 + q * 4) = (uint32)pk;
        }
        // no trailing barrier: slice is wave-private
    }
}

// ---------------- Fused agg1 + gemm2: pipelined LDS-staged gather ---------------
// Per 16-edge batch: issue 8x global_load_lds (8 KB, zero VGPR), then issue the
// NEXT batch's csr index load, then SPLIT-DRAIN: vmcnt(4) -> consume edges 0..7
// while edges 8..15 are still in flight; vmcnt(0) -> consume the rest.

__global__ __launch_bounds__(256) void agg1_fused(
    const uchar* __restrict__ H, const int* __restrict__ csr,
    const int* __restrict__ rowptr, const int* __restrict__ deg,
    const float* __restrict__ dinv, const float* __restrict__ bias,
    const unsigned short* __restrict__ W2t, uchar* __restrict__ H2, int n) {
    __shared__ char stage[4][8192];                // per-wave gather slices
    __shared__ unsigned short tile[16 * 136];      // 16 nodes x 128ch bf16, padded
    int t = threadIdx.x;
    int slot = t >> 4;                              // node slot in block (0..15)
    int v = blockIdx.x * 16 + slot;
    int hl = t & 15;
    int gsel = t & 48;
    int w = t >> 6;                                 // wave id
    int gg = (t >> 4) & 3;                          // group within wave
    bool valid = v < n;
    int vc = valid ? v : 0;
    int base = rowptr[vc];
    int cnt = valid ? deg[vc] : 0;

    f32x2 A0 = (f32x2){0.f, 0.f}, A1 = A0, A2 = A0, A3 = A0;
    f32x2 B0 = A0, B1 = A0, B2 = A0, B3 = A0;

#define ACC128(h, s0, s1, s2, s3)                                   \
    {                                                               \
        s0 += __builtin_amdgcn_cvt_pk_f32_fp8((h).x, false);        \
        s1 += __builtin_amdgcn_cvt_pk_f32_fp8((h).x, true);         \
        s2 += __builtin_amdgcn_cvt_pk_f32_fp8((h).y, false);        \
        s3 += __builtin_amdgcn_cvt_pk_f32_fp8((h).y, true);         \
    }

    char* sl = stage[w];
    const char* rg = sl + gg * 256 + hl * 8;       // consume base for this lane

    int ul = 0;
    if (hl < min(16, cnt)) ul = csr[base + hl];    // batch 0 indices

    for (int j0 = 0; j0 < cnt; j0 += 16) {
        int nj = min(16, cnt - j0);
        // ---- issue: 8x global_load_lds (8 KB in flight, no VGPR held) ----
#pragma unroll
        for (int i = 0; i < 8; i++) {
            int j = i * 2 + (hl >> 3);
            int u = __shfl(ul, j | gsel);
            gload16(H + (((uint32)u << 7) + ((uint32)(hl & 7) << 4)),
                    sl + i * 1024);
        }
        // ---- prefetch next batch's csr indices (drains under consume) ----
        int ul2 = 0;
        int j0n = j0 + 16;
        if (j0n < cnt && hl < min(16, cnt - j0n)) ul2 = csr[base + j0n + hl];
        // ---- split-drain consume ----
        asm volatile("s_waitcnt vmcnt(4)" ::: "memory");
        __builtin_amdgcn_sched_barrier(0);
#pragma unroll
        for (int j = 0; j < 8; j++) {
            if (j < nj) {
                uint2 h = *(const uint2*)(rg + (j >> 1) * 1024 + (j & 1) * 128);
                if (j & 1) { ACC128(h, B0, B1, B2, B3); }
                else       { ACC128(h, A0, A1, A2, A3); }
            }
        }
        asm volatile("s_waitcnt vmcnt(0)" ::: "memory");
        __builtin_amdgcn_sched_barrier(0);
#pragma unroll
        for (int j = 8; j < 16; j++) {
            if (j < nj) {
                uint2 h = *(const uint2*)(rg + (j >> 1) * 1024 + (j & 1) * 128);
                if (j & 1) { ACC128(h, B0, B1, B2, B3); }
                else       { ACC128(h, A0, A1, A2, A3); }
            }
        }
        ul = ul2;
    }
#undef ACC128

    // ---- finish hidden: self-loop + bias + ReLU, pack bf16 ----
    const uint32 co = (uint32)(hl * 8);
    uint4 pk = make_uint4(0, 0, 0, 0);
    if (valid) {
        float dv = dinv[vc];
        uint2 hv = *(const uint2*)(H + (((uint32)vc << 7) + co));
        f32x2 s0 = __builtin_amdgcn_cvt_pk_f32_fp8(hv.x, false);
        f32x2 s1 = __builtin_amdgcn_cvt_pk_f32_fp8(hv.x, true);
        f32x2 s2 = __builtin_amdgcn_cvt_pk_f32_fp8(hv.y, false);
        f32x2 s3 = __builtin_amdgcn_cvt_pk_f32_fp8(hv.y, true);
        const f32x2* bp = (const f32x2*)(bias + hl * 8);
        f32x2 e0 = dv * ((A0 + B0) + 2.f * s0) + bp[0];
        f32x2 e1 = dv * ((A1 + B1) + 2.f * s1) + bp[1];
        f32x2 e2 = dv * ((A2 + B2) + 2.f * s2) + bp[2];
        f32x2 e3 = dv * ((A3 + B3) + 2.f * s3) + bp[3];
        float o0 = fmaxf(e0[0], 0.f), o1 = fmaxf(e0[1], 0.f);
        float o2 = fmaxf(e1[0], 0.f), o3 = fmaxf(e1[1], 0.f);
        float o4 = fmaxf(e2[0], 0.f), o5 = fmaxf(e2[1], 0.f);
        float o6 = fmaxf(e3[0], 0.f), o7 = fmaxf(e3[1], 0.f);
        pk.x = (uint32)f2bf(o0) | ((uint32)f2bf(o1) << 16);
        pk.y = (uint32)f2bf(o2) | ((uint32)f2bf(o3) << 16);
        pk.z = (uint32)f2bf(o4) | ((uint32)f2bf(o5) << 16);
        pk.w = (uint32)f2bf(o6) | ((uint32)f2bf(o7) << 16);
    }
    *(uint4*)&tile[slot * 136 + hl * 8] = pk;
    __syncthreads();

    // ---- gemm2 tail: wave w -> channels w*16..+15 for all 16 nodes ----
    const int l = t & 63;
    const int q = l >> 4, r16 = l & 15;
    f32x4 acc2 = (f32x4){0.f, 0.f, 0.f, 0.f};
#pragma unroll
    for (int s = 0; s < 4; s++) {
        const int k0 = s * 32 + q * 8;
        bf16x8 hf = *(const bf16x8*)&tile[r16 * 136 + k0];                 // node r16
        bf16x8 wf = *(const bf16x8*)(W2t + (size_t)(w * 16 + r16) * 128 + k0); // channel
        acc2 = __builtin_amdgcn_mfma_f32_16x16x32_bf16(wf, hf, acc2, 0, 0, 0);
    }
    const int node = blockIdx.x * 16 + r16;
    if (node < n) {
        const float dv2 = dinv[node];
        int pk2 = 0;
        pk2 = __builtin_amdgcn_cvt_pk_fp8_f32(acc2[0] * dv2, acc2[1] * dv2, pk2, false);
        pk2 = __builtin_amdgcn_cvt_pk_fp8_f32(acc2[2] * dv2, acc2[3] * dv2, pk2, true);
        *(uint32*)(H2 + (size_t)node * 64 + w * 16 + q * 4) = (uint32)pk2;
    }
}

// agg2: 64 ch; same pipelined LDS-staged gather (4 gloads/batch + csr prefetch,
// vmcnt(2)/vmcnt(0) split). log_softmax within group of 16.
__global__ __launch_bounds__(256) void agg_lsm_64(
    const uchar* __restrict__ H, const int* __restrict__ csr,
    const int* __restrict__ rowptr, const int* __restrict__ deg,
    const float* __restrict__ dinv, const float* __restrict__ bias,
    float* __restrict__ out, int n) {
    __shared__ char stage[4][4096];
    int t = threadIdx.x;
    int v = blockIdx.x * 16 + (t >> 4);
    int hl = t & 15;
    int gsel = t & 48;
    int w = t >> 6;
    int gg = (t >> 4) & 3;
    bool valid = v < n;
    int vc = valid ? v : 0;
    int base = rowptr[vc];
    int cnt = valid ? deg[vc] : 0;
    const uint32 co = (uint32)(hl * 4);

    f32x2 A0 = (f32x2){0.f, 0.f}, A1 = A0, B0 = A0, B1 = A0;

#define ACC64(h, s0, s1)                                            \
    {                                                               \
        s0 += __builtin_amdgcn_cvt_pk_f32_fp8((h), false);          \
        s1 += __builtin_amdgcn_cvt_pk_f32_fp8((h), true);           \
    }

    char* sl = stage[w];
    const char* rg = sl + gg * 256 + hl * 4;

    int ul = 0;
    if (hl < min(16, cnt)) ul = csr[base + hl];

    for (int j0 = 0; j0 < cnt; j0 += 16) {
        int nj = min(16, cnt - j0);
#pragma unroll
        for (int i = 0; i < 4; i++) {
            int j = i * 4 + (hl >> 2);
            int u = __shfl(ul, j | gsel);
            gload16(H + (((uint32)u << 6) + ((uint32)(hl & 3) << 4)),
                    sl + i * 1024);
        }
        int ul2 = 0;
        int j0n = j0 + 16;
        if (j0n < cnt && hl < min(16, cnt - j0n)) ul2 = csr[base + j0n + hl];
        asm volatile("s_waitcnt vmcnt(2)" ::: "memory");
        __builtin_amdgcn_sched_barrier(0);
#pragma unroll
        for (int j = 0; j < 8; j++) {
            if (j < nj) {
                uint32 h = *(const uint32*)(rg + (j >> 2) * 1024 + (j & 3) * 64);
                if (j & 1) { ACC64(h, B0, B1); }
                else       { ACC64(h, A0, A1); }
            }
        }
        asm volatile("s_waitcnt vmcnt(0)" ::: "memory");
        __builtin_amdgcn_sched_barrier(0);
#pragma unroll
        for (int j = 8; j < 16; j++) {
            if (j < nj) {
                uint32 h = *(const uint32*)(rg + (j >> 2) * 1024 + (j & 3) * 64);
                if (j & 1) { ACC64(h, B0, B1); }
                else       { ACC64(h, A0, A1); }
            }
        }
        ul = ul2;
    }
#undef ACC64

    float dv = dinv[vc];
    uint32 hv = *(const uint32*)(H + (((uint32)vc << 6) + co));
    f32x2 s0 = __builtin_amdgcn_cvt_pk_f32_fp8(hv, false);
    f32x2 s1 = __builtin_amdgcn_cvt_pk_f32_fp8(hv, true);
    const f32x2* bp = (const f32x2*)(bias + hl * 4);
    f32x2 w0 = dv * ((A0 + B0) + 2.f * s0) + bp[0];
    f32x2 w1 = dv * ((A1 + B1) + 2.f * s1) + bp[1];
    float v0 = w0[0], v1 = w0[1], v2 = w1[0], v3 = w1[1];
    // log_softmax across the 64 channels held by this 16-lane group
    float m = fmaxf(fmaxf(v0, v1), fmaxf(v2, v3));
    for (int o = 8; o > 0; o >>= 1) m = fmaxf(m, __shfl_xor(m, o));
    float e = (__expf(v0 - m) + __expf(v1 - m)) + (__expf(v2 - m) + __expf(v3 - m));
    for (int o = 8; o > 0; o >>= 1) e += __shfl_xor(e, o);
    float ls = m + __logf(e);
    if (valid)
        *(float4*)(out + (size_t)vc * 64 + hl * 4) =
            make_float4(v0 - ls, v1 - ls, v2 - ls, v3 - ls);
}

// ---------------- launch ----------------

extern "C" void kernel_launch(void* const* d_in, const int* in_sizes, int n_in,
                              void* d_out, int out_size, void* d_ws, size_t ws_size,
                              hipStream_t stream) {
    const float* x  = (const float*)d_in[0];
    const int*   ei = (const int*)d_in[1];
    const float* W1 = (const float*)d_in[2];
    const float* b1 = (const float*)d_in[3];
    const float* W2 = (const float*)d_in[4];
    const float* b2 = (const float*)d_in[5];
    float* out = (float*)d_out;

    const int N = in_sizes[0] / IN_CH;  // 100000
    const int E = in_sizes[1] / 2;      // 1600000
    const int* src = ei;
    const int* dst = ei + E;
    const int NB = (N + 255) >> BSH;    // 391 buckets

    char* w = (char*)d_ws;
    size_t off = 0;
    auto alloc = [&](size_t bytes) -> char* {
        char* p = w + off;
        off = (off + bytes + 255) & ~(size_t)255;
        return p;
    };
    int*   deg    = (int*)alloc((size_t)N * 4);
    int*   rowptr = (int*)alloc((size_t)N * 4);
    int*   bcur   = (int*)alloc(512 * 4);
    float* dinv   = (float*)alloc((size_t)N * 4 + 1024);  // +pad for vector tails
    int*   csr    = (int*)alloc((size_t)NB * CAP * 4);    // segmented, 9.6 MB
    unsigned short* W1t = (unsigned short*)alloc(128 * 128 * 2);
    unsigned short* W2t = (unsigned short*)alloc(64 * 128 * 2);
    uchar* H1  = (uchar*)alloc((size_t)N * HID_CH);          // fp8, 12.8 MB
    char*  scratch = alloc((size_t)NB * CAP * 8);            // pairBuf then H2 (19.2 MB)
    uchar* H2  = (uchar*)scratch;        // fp8, 6.4 MB (pairBuf dead after bucket_build)
    int2*  pairBuf = (int2*)scratch;

    hipMemsetAsync(bcur, 0, 512 * 4, stream);

    int gP = (E + PB - 1) / PB;         // 391 partition blocks

    part1_wtrans<<<gP + 96, 256, 0, stream>>>(src, dst, bcur, pairBuf, E, NB, gP,
                                              W1, W2, W1t, W2t);
    bucket_build<<<NB, 256, 0, stream>>>(pairBuf, bcur, rowptr, deg, dinv, csr, N);

    const int nTiles = (N + 63) / 64;   // 1563
    const int gG = min(nTiles, 512);    // persistent grid-stride blocks
    gemm1_mfma<<<gG, 256, 0, stream>>>(x, W1t, dinv, H1, N, nTiles);
    agg1_fused<<<(N + 15) / 16, 256, 0, stream>>>(H1, csr, rowptr, deg, dinv, b1, W2t, H2, N);
    agg_lsm_64<<<(N + 15) / 16, 256, 0, stream>>>(H2, csr, rowptr, deg, dinv, b2, out, N);
}